// Round 7
// baseline (60.299 us; speedup 1.0000x reference)
//
#include <hip/hip_runtime.h>
#include <hip/hip_bf16.h>

typedef __bf16 bf16x8 __attribute__((ext_vector_type(8)));
typedef float f32x4 __attribute__((ext_vector_type(4)));
typedef unsigned int u32;
typedef u32 u32x4 __attribute__((ext_vector_type(4)));

#define BN_EPS 1e-5f
#define RB 4        // rows per batch
#define NBLK 2048
#define NTHR 256

// ---------------- prepass 1: fp32 table -> bf16 table ----------------
__global__ __launch_bounds__(256) void convert_kernel(
    const float* __restrict__ vf, __bf16* __restrict__ tb, int n8)
{
    int i = blockIdx.x * blockDim.x + threadIdx.x;
    const int stride = gridDim.x * blockDim.x;
    for (; i < n8; i += stride) {
        const f32x4 a = ((const f32x4*)vf)[2 * i];
        const f32x4 b = ((const f32x4*)vf)[2 * i + 1];
        bf16x8 o;
        o[0]=(__bf16)a.x; o[1]=(__bf16)a.y; o[2]=(__bf16)a.z; o[3]=(__bf16)a.w;
        o[4]=(__bf16)b.x; o[5]=(__bf16)b.y; o[6]=(__bf16)b.z; o[7]=(__bf16)b.w;
        ((bf16x8*)tb)[i] = o;
    }
}

// ---------------- prepass 2: pack W frags + BN affine + zero row ----------------
__global__ __launch_bounds__(64) void pack_kernel(
    const float* __restrict__ W, const float* __restrict__ bias,
    const float* __restrict__ gamma, const float* __restrict__ beta,
    const float* __restrict__ mean, const float* __restrict__ var,
    __bf16* __restrict__ tb, u32* __restrict__ packB,
    float* __restrict__ SP, float* __restrict__ TP, int N)
{
    const int lane = threadIdx.x;
    const int col = lane & 15, grp = lane >> 4, c0 = grp << 3;
    if (lane < 16) ((u32*)(tb + (size_t)N * 32))[lane] = 0u;   // zero row
    f32x4 s4, t4;
#pragma unroll
    for (int t = 0; t < 4; ++t) {
        const int o = t * 16 + col;
        const f32x4 w0 = *(const f32x4*)(W + o * 32 + c0);
        const f32x4 w1 = *(const f32x4*)(W + o * 32 + c0 + 4);
        bf16x8 f;
        f[0]=(__bf16)w0.x; f[1]=(__bf16)w0.y; f[2]=(__bf16)w0.z; f[3]=(__bf16)w0.w;
        f[4]=(__bf16)w1.x; f[5]=(__bf16)w1.y; f[6]=(__bf16)w1.z; f[7]=(__bf16)w1.w;
        ((bf16x8*)packB)[t * 64 + lane] = f;
        const float s = gamma[o] * rsqrtf(var[o] + BN_EPS);
        s4[t] = s;
        t4[t] = (bias[o] - mean[o]) * s + beta[o];
    }
    ((f32x4*)SP)[lane] = s4;
    ((f32x4*)TP)[lane] = t4;
}

// ---------------- pipelined main kernel helpers ----------------
__device__ __forceinline__ void loadIdx(const int* __restrict__ kidx,
                                        const int* __restrict__ kmask,
                                        int mb, int lane, int elim,
                                        int ci[2], int cm[2])
{
#pragma unroll
    for (int i = 0; i < 2; ++i) {
        int e = mb * 32 + lane + i * 64; e = e < elim ? e : elim;
        ci[i] = __builtin_nontemporal_load(kidx + e);
    }
#pragma unroll
    for (int i = 0; i < 2; ++i) {
        int e = mb * 32 + lane + i * 64; e = e < elim ? e : elim;
        cm[i] = __builtin_nontemporal_load(kmask + e);
    }
}

// shfl-redistribute idx/mask to gather lanes, fold mask -> zero-row N, issue gathers
__device__ __forceinline__ void issueGathers(const __bf16* __restrict__ tb, int N,
                                             const int ci[2], const int cm[2],
                                             int col, int c0, u32x4 g[RB][2])
{
#pragma unroll
    for (int r = 0; r < RB; ++r)
#pragma unroll
        for (int kt = 0; kt < 2; ++kt) {
            const int srcl = ((r & 1) << 5) + (kt << 4) + col;
            int idv = __shfl(ci[r >> 1], srcl, 64);
            int mkv = __shfl(cm[r >> 1], srcl, 64);
            idv = idv < 0 ? 0 : idv;
            idv = (mkv == 0) ? idv : N;
            g[r][kt] = *(const u32x4*)(tb + (size_t)idv * 32 + c0);
        }
}

__device__ __forceinline__ void computeStore(const u32x4 g[RB][2], int mb, int M,
                                             int lane, int grp,
                                             const bf16x8 bfrag[4],
                                             f32x4 Sv, f32x4 Tv,
                                             float* __restrict__ out)
{
    const f32x4 zero4 = {0.f, 0.f, 0.f, 0.f};
#pragma unroll
    for (int r = 0; r < RB; ++r) {
        const int m = mb + r;
        const bf16x8 a0 = __builtin_bit_cast(bf16x8, g[r][0]);
        const bf16x8 a1 = __builtin_bit_cast(bf16x8, g[r][1]);
        float myout = 0.0f;
#pragma unroll
        for (int t = 0; t < 4; ++t) {
            f32x4 d0 = __builtin_amdgcn_mfma_f32_16x16x32_bf16(a0, bfrag[t], zero4, 0, 0, 0);
            f32x4 d1 = __builtin_amdgcn_mfma_f32_16x16x32_bf16(a1, bfrag[t], zero4, 0, 0, 0);
            float v = 0.0f;   // ReLU folded into max
#pragma unroll
            for (int q = 0; q < 4; ++q) {
                v = fmaxf(v, d0[q] * Sv[t] + Tv[t]);
                v = fmaxf(v, d1[q] * Sv[t] + Tv[t]);
            }
            v = fmaxf(v, __shfl_xor(v, 16));
            v = fmaxf(v, __shfl_xor(v, 32));
            if (grp == t) myout = v;
        }
        if (m < M) __builtin_nontemporal_store(myout, out + (size_t)m * 64 + lane);
    }
}

// ---------------- main: persistent waves, 2-stage gather pipeline ----------------
// sched_barrier(0) pins the issue phase BEFORE the compute phase so the
// compiler cannot sink next-batch gathers past computeStore (R5 failure mode:
// VGPR=60 proved buffers weren't kept live). Expect VGPR ~115-125 now.
__global__ __launch_bounds__(256, 4) void down_bf16(
    const __bf16* __restrict__ tb,    // [N+1,32] bf16 (row N = zeros)
    const int*   __restrict__ kidx,   // [M,32]
    const int*   __restrict__ kmask,  // [M,32] (1 = invalid)
    const u32*   __restrict__ packB,
    const float* __restrict__ SP,
    const float* __restrict__ TP,
    float* __restrict__ out,          // [M,64]
    int M, int N)
{
    const int lane = threadIdx.x & 63;
    const int col  = lane & 15;
    const int grp  = lane >> 4;
    const int c0   = grp << 3;

    const int wave_id = blockIdx.x * (NTHR >> 6) + (threadIdx.x >> 6);
    const int nwaves  = NBLK * (NTHR >> 6);
    const int stride  = nwaves * RB;
    const int elim    = M * 32 - 1;

    const int m0 = wave_id * RB;
    if (m0 >= M) return;

    // loop-invariant: B frags + BN affine (L2-hot, same addr across waves)
    bf16x8 bfrag[4];
#pragma unroll
    for (int t = 0; t < 4; ++t)
        bfrag[t] = ((const bf16x8*)packB)[t * 64 + lane];
    const f32x4 Sv = ((const f32x4*)SP)[lane];
    const f32x4 Tv = ((const f32x4*)TP)[lane];

    int ciA[2], cmA[2], ciB[2], cmB[2];
    u32x4 gA[RB][2], gB[RB][2];

    // prologue: idx for batches 0 and 1; gathers for batch 0
    loadIdx(kidx, kmask, m0,          lane, elim, ciA, cmA);
    loadIdx(kidx, kmask, m0 + stride, lane, elim, ciB, cmB);
    issueGathers(tb, N, ciA, cmA, col, c0, gA);

    int mc = m0;
    while (true) {
        // --- half 1: issue batch mc+stride gathers + idx(mc+2s), THEN compute mc ---
        issueGathers(tb, N, ciB, cmB, col, c0, gB);
        loadIdx(kidx, kmask, mc + 2 * stride, lane, elim, ciA, cmA);
        __builtin_amdgcn_sched_barrier(0);   // pin: issues stay above compute
        computeStore(gA, mc, M, lane, grp, bfrag, Sv, Tv, out);
        mc += stride;
        if (mc >= M) break;

        // --- half 2: symmetric ---
        issueGathers(tb, N, ciA, cmA, col, c0, gA);
        loadIdx(kidx, kmask, mc + 2 * stride, lane, elim, ciB, cmB);
        __builtin_amdgcn_sched_barrier(0);
        computeStore(gB, mc, M, lane, grp, bfrag, Sv, Tv, out);
        mc += stride;
        if (mc >= M) break;
    }
}

// ---------------- fallback (fp32 gather, no workspace) ----------------
__global__ __launch_bounds__(256, 4) void down_fp32(
    const float* __restrict__ vf, const int* __restrict__ kidx,
    const int* __restrict__ kmask, const float* __restrict__ W,
    const float* __restrict__ bias, const float* __restrict__ gamma,
    const float* __restrict__ beta, const float* __restrict__ mean,
    const float* __restrict__ var, float* __restrict__ out, int M)
{
    const int lane = threadIdx.x & 63;
    const int col  = lane & 15;
    const int grp  = lane >> 4;
    const int c0   = grp << 3;
    const int waves_per_block = blockDim.x >> 6;
    const int wave_id     = blockIdx.x * waves_per_block + (threadIdx.x >> 6);
    const int total_waves = gridDim.x * waves_per_block;

    bf16x8 bfrag[4];
    float S[4], T[4];
#pragma unroll
    for (int t = 0; t < 4; ++t) {
        const int o = t * 16 + col;
        const f32x4 w0 = *(const f32x4*)(W + o * 32 + c0);
        const f32x4 w1 = *(const f32x4*)(W + o * 32 + c0 + 4);
        bf16x8 f;
        f[0]=(__bf16)w0.x; f[1]=(__bf16)w0.y; f[2]=(__bf16)w0.z; f[3]=(__bf16)w0.w;
        f[4]=(__bf16)w1.x; f[5]=(__bf16)w1.y; f[6]=(__bf16)w1.z; f[7]=(__bf16)w1.w;
        bfrag[t] = f;
        const float s = gamma[o] * rsqrtf(var[o] + BN_EPS);
        S[t] = s;
        T[t] = (bias[o] - mean[o]) * s + beta[o];
    }
    const f32x4 zero4 = {0.f, 0.f, 0.f, 0.f};
    for (int m = wave_id; m < M; m += total_waves) {
        const int* idxp = kidx  + (size_t)m * 32;
        const int* mskp = kmask + (size_t)m * 32;
        bf16x8 afrag[2];
#pragma unroll
        for (int kt = 0; kt < 2; ++kt) {
            const int k = kt * 16 + col;
            int id = idxp[k]; id = id < 0 ? 0 : id;
            const float sel = (mskp[k] == 0) ? 1.0f : 0.0f;
            const float* src = vf + (size_t)id * 32 + c0;
            const f32x4 g0 = *(const f32x4*)(src);
            const f32x4 g1 = *(const f32x4*)(src + 4);
            bf16x8 a;
            a[0]=(__bf16)(g0.x*sel); a[1]=(__bf16)(g0.y*sel);
            a[2]=(__bf16)(g0.z*sel); a[3]=(__bf16)(g0.w*sel);
            a[4]=(__bf16)(g1.x*sel); a[5]=(__bf16)(g1.y*sel);
            a[6]=(__bf16)(g1.z*sel); a[7]=(__bf16)(g1.w*sel);
            afrag[kt] = a;
        }
        float myout = 0.0f;
#pragma unroll
        for (int t = 0; t < 4; ++t) {
            f32x4 d0 = __builtin_amdgcn_mfma_f32_16x16x32_bf16(afrag[0], bfrag[t], zero4, 0, 0, 0);
            f32x4 d1 = __builtin_amdgcn_mfma_f32_16x16x32_bf16(afrag[1], bfrag[t], zero4, 0, 0, 0);
            float v = 0.0f;
#pragma unroll
            for (int q = 0; q < 4; ++q) {
                v = fmaxf(v, d0[q] * S[t] + T[t]);
                v = fmaxf(v, d1[q] * S[t] + T[t]);
            }
            v = fmaxf(v, __shfl_xor(v, 16));
            v = fmaxf(v, __shfl_xor(v, 32));
            if (grp == t) myout = v;
        }
        out[(size_t)m * 64 + lane] = myout;
    }
}

extern "C" void kernel_launch(void* const* d_in, const int* in_sizes, int n_in,
                              void* d_out, int out_size, void* d_ws, size_t ws_size,
                              hipStream_t stream) {
    const float* vf    = (const float*)d_in[0];
    const int*   kidx  = (const int*)  d_in[1];
    const int*   kmask = (const int*)  d_in[2];
    const float* W     = (const float*)d_in[3];
    const float* bias  = (const float*)d_in[4];
    const float* gamma = (const float*)d_in[5];
    const float* beta  = (const float*)d_in[6];
    const float* mean  = (const float*)d_in[7];
    const float* var   = (const float*)d_in[8];
    float* out = (float*)d_out;

    const int NC = in_sizes[0];        // N*32 floats
    const int N  = NC / 32;
    const int M  = in_sizes[1] / 32;   // key_indices is [M,32]

    const size_t tbBytes = ((size_t)N + 1) * 32 * sizeof(__bf16);
    const size_t packOff = tbBytes;
    const size_t need    = packOff + 4096 + 1024 + 1024;

    if (ws_size >= need) {
        __bf16* tb    = (__bf16*)d_ws;
        u32*    packB = (u32*)  ((char*)d_ws + packOff);
        float*  SP    = (float*)((char*)d_ws + packOff + 4096);
        float*  TP    = (float*)((char*)d_ws + packOff + 4096 + 1024);

        pack_kernel<<<1, 64, 0, stream>>>(W, bias, gamma, beta, mean, var,
                                          tb, packB, SP, TP, N);
        convert_kernel<<<2048, 256, 0, stream>>>(vf, tb, NC / 8);
        down_bf16<<<NBLK, NTHR, 0, stream>>>(tb, kidx, kmask, packB, SP, TP,
                                             out, M, N);
    } else {
        down_fp32<<<2048, 256, 0, stream>>>(vf, kidx, kmask, W, bias, gamma,
                                            beta, mean, var, out, M);
    }
}

// Round 8
// 59.455 us; speedup vs baseline: 1.0142x; 1.0142x over previous
//
#include <hip/hip_runtime.h>
#include <hip/hip_bf16.h>

typedef __bf16 bf16x8 __attribute__((ext_vector_type(8)));
typedef float f32x4 __attribute__((ext_vector_type(4)));
typedef unsigned int u32;
typedef u32 u32x4 __attribute__((ext_vector_type(4)));

#define BN_EPS 1e-5f
#define RB 4        // rows per batch
#define NBLK 2048
#define NTHR 256

// ---------------- prepass 1: fp32 table -> bf16 table ----------------
__global__ __launch_bounds__(256) void convert_kernel(
    const float* __restrict__ vf, __bf16* __restrict__ tb, int n8)
{
    int i = blockIdx.x * blockDim.x + threadIdx.x;
    const int stride = gridDim.x * blockDim.x;
    for (; i < n8; i += stride) {
        const f32x4 a = ((const f32x4*)vf)[2 * i];
        const f32x4 b = ((const f32x4*)vf)[2 * i + 1];
        bf16x8 o;
        o[0]=(__bf16)a.x; o[1]=(__bf16)a.y; o[2]=(__bf16)a.z; o[3]=(__bf16)a.w;
        o[4]=(__bf16)b.x; o[5]=(__bf16)b.y; o[6]=(__bf16)b.z; o[7]=(__bf16)b.w;
        ((bf16x8*)tb)[i] = o;
    }
}

// ---------------- prepass 2: pack W frags + BN affine + zero row ----------------
__global__ __launch_bounds__(64) void pack_kernel(
    const float* __restrict__ W, const float* __restrict__ bias,
    const float* __restrict__ gamma, const float* __restrict__ beta,
    const float* __restrict__ mean, const float* __restrict__ var,
    __bf16* __restrict__ tb, u32* __restrict__ packB,
    float* __restrict__ SP, float* __restrict__ TP, int N)
{
    const int lane = threadIdx.x;
    const int col = lane & 15, grp = lane >> 4, c0 = grp << 3;
    if (lane < 16) ((u32*)(tb + (size_t)N * 32))[lane] = 0u;   // zero row
    f32x4 s4, t4;
#pragma unroll
    for (int t = 0; t < 4; ++t) {
        const int o = t * 16 + col;
        const f32x4 w0 = *(const f32x4*)(W + o * 32 + c0);
        const f32x4 w1 = *(const f32x4*)(W + o * 32 + c0 + 4);
        bf16x8 f;
        f[0]=(__bf16)w0.x; f[1]=(__bf16)w0.y; f[2]=(__bf16)w0.z; f[3]=(__bf16)w0.w;
        f[4]=(__bf16)w1.x; f[5]=(__bf16)w1.y; f[6]=(__bf16)w1.z; f[7]=(__bf16)w1.w;
        ((bf16x8*)packB)[t * 64 + lane] = f;
        const float s = gamma[o] * rsqrtf(var[o] + BN_EPS);
        s4[t] = s;
        t4[t] = (bias[o] - mean[o]) * s + beta[o];
    }
    ((f32x4*)SP)[lane] = s4;
    ((f32x4*)TP)[lane] = t4;
}

// ---------------- pipelined main kernel helpers ----------------
__device__ __forceinline__ void loadIdx(const int* __restrict__ kidx,
                                        const int* __restrict__ kmask,
                                        int mb, int lane, int elim,
                                        int ci[2], int cm[2])
{
#pragma unroll
    for (int i = 0; i < 2; ++i) {
        int e = mb * 32 + lane + i * 64; e = e < elim ? e : elim;
        ci[i] = __builtin_nontemporal_load(kidx + e);
    }
#pragma unroll
    for (int i = 0; i < 2; ++i) {
        int e = mb * 32 + lane + i * 64; e = e < elim ? e : elim;
        cm[i] = __builtin_nontemporal_load(kmask + e);
    }
}

// shfl-redistribute idx/mask to gather lanes, fold mask -> zero-row N, issue gathers
__device__ __forceinline__ void issueGathers(const __bf16* __restrict__ tb, int N,
                                             const int ci[2], const int cm[2],
                                             int col, int c0, u32x4 g[RB][2])
{
#pragma unroll
    for (int r = 0; r < RB; ++r)
#pragma unroll
        for (int kt = 0; kt < 2; ++kt) {
            const int srcl = ((r & 1) << 5) + (kt << 4) + col;
            int idv = __shfl(ci[r >> 1], srcl, 64);
            int mkv = __shfl(cm[r >> 1], srcl, 64);
            idv = idv < 0 ? 0 : idv;
            idv = (mkv == 0) ? idv : N;
            g[r][kt] = *(const u32x4*)(tb + (size_t)idv * 32 + c0);
        }
}

__device__ __forceinline__ void computeStore(const u32x4 g[RB][2], int mb, int M,
                                             int lane, int grp,
                                             const bf16x8 bfrag[4],
                                             f32x4 Sv, f32x4 Tv,
                                             float* __restrict__ out)
{
    const f32x4 zero4 = {0.f, 0.f, 0.f, 0.f};
#pragma unroll
    for (int r = 0; r < RB; ++r) {
        const int m = mb + r;
        const bf16x8 a0 = __builtin_bit_cast(bf16x8, g[r][0]);
        const bf16x8 a1 = __builtin_bit_cast(bf16x8, g[r][1]);
        float myout = 0.0f;
#pragma unroll
        for (int t = 0; t < 4; ++t) {
            f32x4 d0 = __builtin_amdgcn_mfma_f32_16x16x32_bf16(a0, bfrag[t], zero4, 0, 0, 0);
            f32x4 d1 = __builtin_amdgcn_mfma_f32_16x16x32_bf16(a1, bfrag[t], zero4, 0, 0, 0);
            float v = 0.0f;   // ReLU folded into max
#pragma unroll
            for (int q = 0; q < 4; ++q) {
                v = fmaxf(v, d0[q] * Sv[t] + Tv[t]);
                v = fmaxf(v, d1[q] * Sv[t] + Tv[t]);
            }
            v = fmaxf(v, __shfl_xor(v, 16));
            v = fmaxf(v, __shfl_xor(v, 32));
            if (grp == t) myout = v;
        }
        if (m < M) __builtin_nontemporal_store(myout, out + (size_t)m * 64 + lane);
    }
}

// ---------------- main: persistent waves, 2-stage gather pipeline ----------------
// R6's sched_barrier(0) failed to pin (VGPR stayed 60 -> IR-level sinking).
// asm volatile "memory" clobber is an IR-level memory barrier: the next-batch
// gathers issued above it CANNOT sink below -> payload stays live, counted
// vmcnt wait instead of issue->drain. Pin check: VGPR_Count must be >=110.
__global__ __launch_bounds__(256, 4) void down_bf16(
    const __bf16* __restrict__ tb,    // [N+1,32] bf16 (row N = zeros)
    const int*   __restrict__ kidx,   // [M,32]
    const int*   __restrict__ kmask,  // [M,32] (1 = invalid)
    const u32*   __restrict__ packB,
    const float* __restrict__ SP,
    const float* __restrict__ TP,
    float* __restrict__ out,          // [M,64]
    int M, int N)
{
    const int lane = threadIdx.x & 63;
    const int col  = lane & 15;
    const int grp  = lane >> 4;
    const int c0   = grp << 3;

    const int wave_id = blockIdx.x * (NTHR >> 6) + (threadIdx.x >> 6);
    const int nwaves  = NBLK * (NTHR >> 6);
    const int stride  = nwaves * RB;
    const int elim    = M * 32 - 1;

    const int m0 = wave_id * RB;
    if (m0 >= M) return;

    // loop-invariant: B frags + BN affine (L2-hot, same addr across waves)
    bf16x8 bfrag[4];
#pragma unroll
    for (int t = 0; t < 4; ++t)
        bfrag[t] = ((const bf16x8*)packB)[t * 64 + lane];
    const f32x4 Sv = ((const f32x4*)SP)[lane];
    const f32x4 Tv = ((const f32x4*)TP)[lane];

    int ciA[2], cmA[2], ciB[2], cmB[2];
    u32x4 gA[RB][2], gB[RB][2];

    // prologue: idx for batches 0 and 1; gathers for batch 0
    loadIdx(kidx, kmask, m0,          lane, elim, ciA, cmA);
    loadIdx(kidx, kmask, m0 + stride, lane, elim, ciB, cmB);
    issueGathers(tb, N, ciA, cmA, col, c0, gA);

    int mc = m0;
    while (true) {
        // --- half 1: issue batch mc+stride gathers + idx(mc+2s), THEN compute mc ---
        issueGathers(tb, N, ciB, cmB, col, c0, gB);
        loadIdx(kidx, kmask, mc + 2 * stride, lane, elim, ciA, cmA);
        asm volatile("" ::: "memory");   // IR-level pin: loads may not sink below
        computeStore(gA, mc, M, lane, grp, bfrag, Sv, Tv, out);
        mc += stride;
        if (mc >= M) break;

        // --- half 2: symmetric ---
        issueGathers(tb, N, ciA, cmA, col, c0, gA);
        loadIdx(kidx, kmask, mc + 2 * stride, lane, elim, ciB, cmB);
        asm volatile("" ::: "memory");
        computeStore(gB, mc, M, lane, grp, bfrag, Sv, Tv, out);
        mc += stride;
        if (mc >= M) break;
    }
}

// ---------------- fallback (fp32 gather, no workspace) ----------------
__global__ __launch_bounds__(256, 4) void down_fp32(
    const float* __restrict__ vf, const int* __restrict__ kidx,
    const int* __restrict__ kmask, const float* __restrict__ W,
    const float* __restrict__ bias, const float* __restrict__ gamma,
    const float* __restrict__ beta, const float* __restrict__ mean,
    const float* __restrict__ var, float* __restrict__ out, int M)
{
    const int lane = threadIdx.x & 63;
    const int col  = lane & 15;
    const int grp  = lane >> 4;
    const int c0   = grp << 3;
    const int waves_per_block = blockDim.x >> 6;
    const int wave_id     = blockIdx.x * waves_per_block + (threadIdx.x >> 6);
    const int total_waves = gridDim.x * waves_per_block;

    bf16x8 bfrag[4];
    float S[4], T[4];
#pragma unroll
    for (int t = 0; t < 4; ++t) {
        const int o = t * 16 + col;
        const f32x4 w0 = *(const f32x4*)(W + o * 32 + c0);
        const f32x4 w1 = *(const f32x4*)(W + o * 32 + c0 + 4);
        bf16x8 f;
        f[0]=(__bf16)w0.x; f[1]=(__bf16)w0.y; f[2]=(__bf16)w0.z; f[3]=(__bf16)w0.w;
        f[4]=(__bf16)w1.x; f[5]=(__bf16)w1.y; f[6]=(__bf16)w1.z; f[7]=(__bf16)w1.w;
        bfrag[t] = f;
        const float s = gamma[o] * rsqrtf(var[o] + BN_EPS);
        S[t] = s;
        T[t] = (bias[o] - mean[o]) * s + beta[o];
    }
    const f32x4 zero4 = {0.f, 0.f, 0.f, 0.f};
    for (int m = wave_id; m < M; m += total_waves) {
        const int* idxp = kidx  + (size_t)m * 32;
        const int* mskp = kmask + (size_t)m * 32;
        bf16x8 afrag[2];
#pragma unroll
        for (int kt = 0; kt < 2; ++kt) {
            const int k = kt * 16 + col;
            int id = idxp[k]; id = id < 0 ? 0 : id;
            const float sel = (mskp[k] == 0) ? 1.0f : 0.0f;
            const float* src = vf + (size_t)id * 32 + c0;
            const f32x4 g0 = *(const f32x4*)(src);
            const f32x4 g1 = *(const f32x4*)(src + 4);
            bf16x8 a;
            a[0]=(__bf16)(g0.x*sel); a[1]=(__bf16)(g0.y*sel);
            a[2]=(__bf16)(g0.z*sel); a[3]=(__bf16)(g0.w*sel);
            a[4]=(__bf16)(g1.x*sel); a[5]=(__bf16)(g1.y*sel);
            a[6]=(__bf16)(g1.z*sel); a[7]=(__bf16)(g1.w*sel);
            afrag[kt] = a;
        }
        float myout = 0.0f;
#pragma unroll
        for (int t = 0; t < 4; ++t) {
            f32x4 d0 = __builtin_amdgcn_mfma_f32_16x16x32_bf16(afrag[0], bfrag[t], zero4, 0, 0, 0);
            f32x4 d1 = __builtin_amdgcn_mfma_f32_16x16x32_bf16(afrag[1], bfrag[t], zero4, 0, 0, 0);
            float v = 0.0f;
#pragma unroll
            for (int q = 0; q < 4; ++q) {
                v = fmaxf(v, d0[q] * S[t] + T[t]);
                v = fmaxf(v, d1[q] * S[t] + T[t]);
            }
            v = fmaxf(v, __shfl_xor(v, 16));
            v = fmaxf(v, __shfl_xor(v, 32));
            if (grp == t) myout = v;
        }
        out[(size_t)m * 64 + lane] = myout;
    }
}

extern "C" void kernel_launch(void* const* d_in, const int* in_sizes, int n_in,
                              void* d_out, int out_size, void* d_ws, size_t ws_size,
                              hipStream_t stream) {
    const float* vf    = (const float*)d_in[0];
    const int*   kidx  = (const int*)  d_in[1];
    const int*   kmask = (const int*)  d_in[2];
    const float* W     = (const float*)d_in[3];
    const float* bias  = (const float*)d_in[4];
    const float* gamma = (const float*)d_in[5];
    const float* beta  = (const float*)d_in[6];
    const float* mean  = (const float*)d_in[7];
    const float* var   = (const float*)d_in[8];
    float* out = (float*)d_out;

    const int NC = in_sizes[0];        // N*32 floats
    const int N  = NC / 32;
    const int M  = in_sizes[1] / 32;   // key_indices is [M,32]

    const size_t tbBytes = ((size_t)N + 1) * 32 * sizeof(__bf16);
    const size_t packOff = tbBytes;
    const size_t need    = packOff + 4096 + 1024 + 1024;

    if (ws_size >= need) {
        __bf16* tb    = (__bf16*)d_ws;
        u32*    packB = (u32*)  ((char*)d_ws + packOff);
        float*  SP    = (float*)((char*)d_ws + packOff + 4096);
        float*  TP    = (float*)((char*)d_ws + packOff + 4096 + 1024);

        pack_kernel<<<1, 64, 0, stream>>>(W, bias, gamma, beta, mean, var,
                                          tb, packB, SP, TP, N);
        convert_kernel<<<2048, 256, 0, stream>>>(vf, tb, NC / 8);
        down_bf16<<<NBLK, NTHR, 0, stream>>>(tb, kidx, kmask, packB, SP, TP,
                                             out, M, N);
    } else {
        down_fp32<<<2048, 256, 0, stream>>>(vf, kidx, kmask, W, bias, gamma,
                                            beta, mean, var, out, M);
    }
}

// Round 9
// 59.047 us; speedup vs baseline: 1.0212x; 1.0069x over previous
//
#include <hip/hip_runtime.h>
#include <hip/hip_bf16.h>

typedef __bf16 bf16x8 __attribute__((ext_vector_type(8)));
typedef float f32x4 __attribute__((ext_vector_type(4)));
typedef unsigned int u32;
typedef u32 u32x4 __attribute__((ext_vector_type(4)));

#define BN_EPS 1e-5f

// ---------------- prepass 1: fp32 table -> bf16 table ----------------
__global__ __launch_bounds__(256) void convert_kernel(
    const float* __restrict__ vf, __bf16* __restrict__ tb, int n8)
{
    int i = blockIdx.x * blockDim.x + threadIdx.x;
    const int stride = gridDim.x * blockDim.x;
    for (; i < n8; i += stride) {
        const f32x4 a = ((const f32x4*)vf)[2 * i];
        const f32x4 b = ((const f32x4*)vf)[2 * i + 1];
        bf16x8 o;
        o[0]=(__bf16)a.x; o[1]=(__bf16)a.y; o[2]=(__bf16)a.z; o[3]=(__bf16)a.w;
        o[4]=(__bf16)b.x; o[5]=(__bf16)b.y; o[6]=(__bf16)b.z; o[7]=(__bf16)b.w;
        ((bf16x8*)tb)[i] = o;
    }
}

// ---------------- prepass 2: pack W frags + BN affine + zero row ----------------
__global__ __launch_bounds__(64) void pack_kernel(
    const float* __restrict__ W, const float* __restrict__ bias,
    const float* __restrict__ gamma, const float* __restrict__ beta,
    const float* __restrict__ mean, const float* __restrict__ var,
    __bf16* __restrict__ tb, u32* __restrict__ packB,
    float* __restrict__ SP, float* __restrict__ TP, int N)
{
    const int lane = threadIdx.x;
    const int col = lane & 15, grp = lane >> 4, c0 = grp << 3;
    if (lane < 16) ((u32*)(tb + (size_t)N * 32))[lane] = 0u;   // zero row
    f32x4 s4, t4;
#pragma unroll
    for (int t = 0; t < 4; ++t) {
        const int o = t * 16 + col;
        const f32x4 w0 = *(const f32x4*)(W + o * 32 + c0);
        const f32x4 w1 = *(const f32x4*)(W + o * 32 + c0 + 4);
        bf16x8 f;
        f[0]=(__bf16)w0.x; f[1]=(__bf16)w0.y; f[2]=(__bf16)w0.z; f[3]=(__bf16)w0.w;
        f[4]=(__bf16)w1.x; f[5]=(__bf16)w1.y; f[6]=(__bf16)w1.z; f[7]=(__bf16)w1.w;
        ((bf16x8*)packB)[t * 64 + lane] = f;
        const float s = gamma[o] * rsqrtf(var[o] + BN_EPS);
        s4[t] = s;
        t4[t] = (bias[o] - mean[o]) * s + beta[o];
    }
    ((f32x4*)SP)[lane] = s4;
    ((f32x4*)TP)[lane] = t4;
}

// ---------------- main: straight-line wave = 8 rows, asm-pinned 16-deep gathers ----
// Depth is owned via volatile asm global_load_dwordx4: the compiler MUST keep
// all 16 dest quads (64 VGPR) live; counted vmcnt(8)/vmcnt(4) + sched_barrier(0)
// keep 8 gathers in flight under the first compute half (rule #18 fence).
// Compiler-tracked loads (idx, packB, SP, TP) are fully retired via fake-use
// BEFORE the first asm gather, so hipcc never emits its own vmcnt in between.
__global__ __launch_bounds__(256, 4) void down_bf16(
    const __bf16* __restrict__ tb,    // [N+1,32] bf16 (row N = zeros)
    const int*   __restrict__ kidx,   // [M,32]
    const int*   __restrict__ kmask,  // [M,32] (1 = invalid)
    const u32*   __restrict__ packB,
    const float* __restrict__ SP,
    const float* __restrict__ TP,
    float* __restrict__ out,          // [M,64]
    int M, int N)
{
    const int lane = threadIdx.x & 63;
    const int col  = lane & 15;
    const int grp  = lane >> 4;
    const int c0   = grp << 3;

    const int wave_id = blockIdx.x * 4 + (threadIdx.x >> 6);
    const int m0 = wave_id * 8;            // 8 rows per wave, one-shot
    if (m0 >= M) return;

    // ---- coalesced idx/mask: 8 rows x 32 = 256 elems = 4 loads each ----
    const int elim  = M * 32 - 1;
    const int ebase = m0 * 32 + lane;
    int ci[4], cm[4];
#pragma unroll
    for (int i = 0; i < 4; ++i) {
        int e = ebase + i * 64; e = e < elim ? e : elim;
        ci[i] = __builtin_nontemporal_load(kidx + e);
    }
#pragma unroll
    for (int i = 0; i < 4; ++i) {
        int e = ebase + i * 64; e = e < elim ? e : elim;
        cm[i] = __builtin_nontemporal_load(kmask + e);
    }

    // ---- B frags + BN affine (L2-hot) ----
    bf16x8 bfrag[4];
#pragma unroll
    for (int t = 0; t < 4; ++t)
        bfrag[t] = ((const bf16x8*)packB)[t * 64 + lane];
    f32x4 Sv = ((const f32x4*)SP)[lane];
    f32x4 Tv = ((const f32x4*)TP)[lane];

    // ---- shfl-redistribute idx/mask; fold mask -> zero row N ----
    int fid[8][2];
#pragma unroll
    for (int r = 0; r < 8; ++r)
#pragma unroll
        for (int kt = 0; kt < 2; ++kt) {
            const int srcl = ((r & 1) << 5) + (kt << 4) + col;
            int idv = __shfl(ci[r >> 1], srcl, 64);
            int mkv = __shfl(cm[r >> 1], srcl, 64);
            idv = idv < 0 ? 0 : idv;
            fid[r][kt] = (mkv == 0) ? idv : N;
        }

    // ---- retire all compiler-tracked loads HERE (their waitcnts land above) ----
    asm volatile("" : "+v"(bfrag[0]), "+v"(bfrag[1]), "+v"(bfrag[2]), "+v"(bfrag[3]));
    asm volatile("" : "+v"(Sv), "+v"(Tv));

    // ---- issue ALL 16 gathers via volatile asm (pinned depth, 64 VGPR live) ----
    u32x4 g[8][2];
#pragma unroll
    for (int r = 0; r < 8; ++r)
#pragma unroll
        for (int kt = 0; kt < 2; ++kt) {
            unsigned long long addr =
                (unsigned long long)(tb + (size_t)fid[r][kt] * 32 + c0);
            asm volatile("global_load_dwordx4 %0, %1, off"
                         : "=&v"(g[r][kt]) : "v"(addr));
        }

    const f32x4 zero4 = {0.f, 0.f, 0.f, 0.f};

    // ---- half 1: rows 0..3 (8 gathers for rows 4..7 remain in flight) ----
    asm volatile("s_waitcnt vmcnt(8)" ::: "memory");
    __builtin_amdgcn_sched_barrier(0);
#pragma unroll
    for (int r = 0; r < 4; ++r) {
        const int m = m0 + r;
        const bf16x8 a0 = __builtin_bit_cast(bf16x8, g[r][0]);
        const bf16x8 a1 = __builtin_bit_cast(bf16x8, g[r][1]);
        float myout = 0.0f;
#pragma unroll
        for (int t = 0; t < 4; ++t) {
            f32x4 d0 = __builtin_amdgcn_mfma_f32_16x16x32_bf16(a0, bfrag[t], zero4, 0, 0, 0);
            f32x4 d1 = __builtin_amdgcn_mfma_f32_16x16x32_bf16(a1, bfrag[t], zero4, 0, 0, 0);
            float v = 0.0f;   // ReLU folded into max
#pragma unroll
            for (int q = 0; q < 4; ++q) {
                v = fmaxf(v, d0[q] * Sv[t] + Tv[t]);
                v = fmaxf(v, d1[q] * Sv[t] + Tv[t]);
            }
            v = fmaxf(v, __shfl_xor(v, 16));
            v = fmaxf(v, __shfl_xor(v, 32));
            if (grp == t) myout = v;
        }
        if (m < M) __builtin_nontemporal_store(myout, out + (size_t)m * 64 + lane);
    }

    // ---- half 2: rows 4..7 (<=4 newest outstanding = our stores) ----
    asm volatile("s_waitcnt vmcnt(4)" ::: "memory");
    __builtin_amdgcn_sched_barrier(0);
#pragma unroll
    for (int r = 4; r < 8; ++r) {
        const int m = m0 + r;
        const bf16x8 a0 = __builtin_bit_cast(bf16x8, g[r][0]);
        const bf16x8 a1 = __builtin_bit_cast(bf16x8, g[r][1]);
        float myout = 0.0f;
#pragma unroll
        for (int t = 0; t < 4; ++t) {
            f32x4 d0 = __builtin_amdgcn_mfma_f32_16x16x32_bf16(a0, bfrag[t], zero4, 0, 0, 0);
            f32x4 d1 = __builtin_amdgcn_mfma_f32_16x16x32_bf16(a1, bfrag[t], zero4, 0, 0, 0);
            float v = 0.0f;
#pragma unroll
            for (int q = 0; q < 4; ++q) {
                v = fmaxf(v, d0[q] * Sv[t] + Tv[t]);
                v = fmaxf(v, d1[q] * Sv[t] + Tv[t]);
            }
            v = fmaxf(v, __shfl_xor(v, 16));
            v = fmaxf(v, __shfl_xor(v, 32));
            if (grp == t) myout = v;
        }
        if (m < M) __builtin_nontemporal_store(myout, out + (size_t)m * 64 + lane);
    }
}

// ---------------- fallback (fp32 gather, no workspace) ----------------
__global__ __launch_bounds__(256, 4) void down_fp32(
    const float* __restrict__ vf, const int* __restrict__ kidx,
    const int* __restrict__ kmask, const float* __restrict__ W,
    const float* __restrict__ bias, const float* __restrict__ gamma,
    const float* __restrict__ beta, const float* __restrict__ mean,
    const float* __restrict__ var, float* __restrict__ out, int M)
{
    const int lane = threadIdx.x & 63;
    const int col  = lane & 15;
    const int grp  = lane >> 4;
    const int c0   = grp << 3;
    const int waves_per_block = blockDim.x >> 6;
    const int wave_id     = blockIdx.x * waves_per_block + (threadIdx.x >> 6);
    const int total_waves = gridDim.x * waves_per_block;

    bf16x8 bfrag[4];
    float S[4], T[4];
#pragma unroll
    for (int t = 0; t < 4; ++t) {
        const int o = t * 16 + col;
        const f32x4 w0 = *(const f32x4*)(W + o * 32 + c0);
        const f32x4 w1 = *(const f32x4*)(W + o * 32 + c0 + 4);
        bf16x8 f;
        f[0]=(__bf16)w0.x; f[1]=(__bf16)w0.y; f[2]=(__bf16)w0.z; f[3]=(__bf16)w0.w;
        f[4]=(__bf16)w1.x; f[5]=(__bf16)w1.y; f[6]=(__bf16)w1.z; f[7]=(__bf16)w1.w;
        bfrag[t] = f;
        const float s = gamma[o] * rsqrtf(var[o] + BN_EPS);
        S[t] = s;
        T[t] = (bias[o] - mean[o]) * s + beta[o];
    }
    const f32x4 zero4 = {0.f, 0.f, 0.f, 0.f};
    for (int m = wave_id; m < M; m += total_waves) {
        const int* idxp = kidx  + (size_t)m * 32;
        const int* mskp = kmask + (size_t)m * 32;
        bf16x8 afrag[2];
#pragma unroll
        for (int kt = 0; kt < 2; ++kt) {
            const int k = kt * 16 + col;
            int id = idxp[k]; id = id < 0 ? 0 : id;
            const float sel = (mskp[k] == 0) ? 1.0f : 0.0f;
            const float* src = vf + (size_t)id * 32 + c0;
            const f32x4 g0 = *(const f32x4*)(src);
            const f32x4 g1 = *(const f32x4*)(src + 4);
            bf16x8 a;
            a[0]=(__bf16)(g0.x*sel); a[1]=(__bf16)(g0.y*sel);
            a[2]=(__bf16)(g0.z*sel); a[3]=(__bf16)(g0.w*sel);
            a[4]=(__bf16)(g1.x*sel); a[5]=(__bf16)(g1.y*sel);
            a[6]=(__bf16)(g1.z*sel); a[7]=(__bf16)(g1.w*sel);
            afrag[kt] = a;
        }
        float myout = 0.0f;
#pragma unroll
        for (int t = 0; t < 4; ++t) {
            f32x4 d0 = __builtin_amdgcn_mfma_f32_16x16x32_bf16(afrag[0], bfrag[t], zero4, 0, 0, 0);
            f32x4 d1 = __builtin_amdgcn_mfma_f32_16x16x32_bf16(afrag[1], bfrag[t], zero4, 0, 0, 0);
            float v = 0.0f;
#pragma unroll
            for (int q = 0; q < 4; ++q) {
                v = fmaxf(v, d0[q] * S[t] + T[t]);
                v = fmaxf(v, d1[q] * S[t] + T[t]);
            }
            v = fmaxf(v, __shfl_xor(v, 16));
            v = fmaxf(v, __shfl_xor(v, 32));
            if (grp == t) myout = v;
        }
        out[(size_t)m * 64 + lane] = myout;
    }
}

extern "C" void kernel_launch(void* const* d_in, const int* in_sizes, int n_in,
                              void* d_out, int out_size, void* d_ws, size_t ws_size,
                              hipStream_t stream) {
    const float* vf    = (const float*)d_in[0];
    const int*   kidx  = (const int*)  d_in[1];
    const int*   kmask = (const int*)  d_in[2];
    const float* W     = (const float*)d_in[3];
    const float* bias  = (const float*)d_in[4];
    const float* gamma = (const float*)d_in[5];
    const float* beta  = (const float*)d_in[6];
    const float* mean  = (const float*)d_in[7];
    const float* var   = (const float*)d_in[8];
    float* out = (float*)d_out;

    const int NC = in_sizes[0];        // N*32 floats
    const int N  = NC / 32;
    const int M  = in_sizes[1] / 32;   // key_indices is [M,32]

    const size_t tbBytes = ((size_t)N + 1) * 32 * sizeof(__bf16);
    const size_t packOff = tbBytes;
    const size_t need    = packOff + 4096 + 1024 + 1024;

    if (ws_size >= need) {
        __bf16* tb    = (__bf16*)d_ws;
        u32*    packB = (u32*)  ((char*)d_ws + packOff);
        float*  SP    = (float*)((char*)d_ws + packOff + 4096);
        float*  TP    = (float*)((char*)d_ws + packOff + 4096 + 1024);

        pack_kernel<<<1, 64, 0, stream>>>(W, bias, gamma, beta, mean, var,
                                          tb, packB, SP, TP, N);
        convert_kernel<<<2048, 256, 0, stream>>>(vf, tb, NC / 8);

        const int rows_per_block = 32;          // 4 waves x 8 rows
        const int blocks = (M + rows_per_block - 1) / rows_per_block;
        down_bf16<<<blocks, 256, 0, stream>>>(tb, kidx, kmask, packB, SP, TP,
                                              out, M, N);
    } else {
        down_fp32<<<2048, 256, 0, stream>>>(vf, kidx, kmask, W, bias, gamma,
                                            beta, mean, var, out, M);
    }
}